// Round 17
// baseline (128.668 us; speedup 1.0000x reference)
//
#include <hip/hip_runtime.h>

#define T_LEN  4096
#define KS     16
#define NSEG   8           // T segments (512 output steps each)
#define SEG_CH 32          // output chunks per segment
#define WARM_CH 24         // 384 warm-up steps; flips cease by warm-190 (margin calc R16)

#define ALPHA_F 0.9048374180359595f
#define BETA_F  0.09516258196404048f
#define THETA_F 0.5f

// Full-wave (64-lane) max, result in ALL lanes. Verbatim from the passing
// R3-R16 kernels (manual s_nop hazard handling inside asm).
__device__ __forceinline__ float wave64_max_all(float v) {
  float m, t;
  asm("s_nop 1\n\t"
      "v_max_f32 %0, %2, %2 quad_perm:[1,0,3,2] row_mask:0xf bank_mask:0xf\n\t"
      "s_nop 1\n\t"
      "v_max_f32 %0, %0, %0 quad_perm:[2,3,0,1] row_mask:0xf bank_mask:0xf\n\t"
      "s_nop 1\n\t"
      "v_max_f32 %0, %0, %0 row_half_mirror row_mask:0xf bank_mask:0xf\n\t"
      "s_nop 1\n\t"
      "v_max_f32 %0, %0, %0 row_mirror row_mask:0xf bank_mask:0xf\n\t"
      "v_mov_b32 %1, %0\n\t"
      "s_nop 1\n\t"
      "v_permlane32_swap_b32 %1, %0\n\t"
      "s_nop 1\n\t"
      "v_max_f32 %0, %0, %1\n\t"
      "v_mov_b32 %1, %0\n\t"
      "s_nop 1\n\t"
      "v_permlane16_swap_b32 %1, %0\n\t"
      "s_nop 1\n\t"
      "v_max_f32 %0, %0, %1"
      : "=&v"(m), "=&v"(t)
      : "v"(v));
  return m;
}

__global__ __launch_bounds__(64, 2)
void convlif_wta_kernel(const float* __restrict__ x, const float* __restrict__ W,
                        float* __restrict__ out) {
  const int blk  = blockIdx.x;
  const int b    = blk >> 3;          // batch
  const int seg  = blk & (NSEG - 1);  // time segment
  const int lane = threadIdx.x;       // channel k

  const int cout0  = seg * SEG_CH;                                  // first output chunk
  const int cstart = (cout0 > WARM_CH) ? (cout0 - WARM_CH) : 0;     // warm-up start
  const int cend   = cout0 + SEG_CH;

  // per-lane conv weights W[k][0..15]
  float w[KS];
  {
    const float4* w4 = reinterpret_cast<const float4*>(W + lane * KS);
    #pragma unroll
    for (int q = 0; q < 4; ++q) {
      float4 a = w4[q];
      w[4*q+0] = a.x; w[4*q+1] = a.y; w[4*q+2] = a.z; w[4*q+3] = a.w;
    }
  }

  const float4* xv4 = reinterpret_cast<const float4*>(x + (size_t)b * T_LEN);
  float* orow = out + ((size_t)(b * 64 + lane)) * T_LEN;   // this lane's channel row

  // rolling x window: cur[0..7] = quads 4c-4 .. 4c+3 = x[16c-16 .. 16c+15]
  // (for c==0 the first half is garbage; overridden with zeros at xf assembly)
  float4 cur[8];
  {
    const int c  = cstart;
    const int bq = 4 * c - 4;
    const int b0 = (bq < 0) ? 0 : bq;
    #pragma unroll
    for (int q = 0; q < 4; ++q) cur[q] = xv4[b0 + q];
    #pragma unroll
    for (int q = 0; q < 4; ++q) cur[4 + q] = xv4[4 * c + q];
  }

  float v = 0.0f;   // exact for seg 0 (warm-up reaches t=0); speculative else

  // ---------------- phase 1: warm-up (no sv, no stores) -------------------
  for (int c = cstart; c < cout0; ++c) {
    float4 nx0 = xv4[4*(c+1) + 0], nx1 = xv4[4*(c+1) + 1];   // c+1 <= cout0 < cend
    float4 nx2 = xv4[4*(c+1) + 2], nx3 = xv4[4*(c+1) + 3];

    float xf[32];
    if (c == 0) {
      #pragma unroll
      for (int m = 0; m < 16; ++m) xf[m] = 0.0f;
    } else {
      #pragma unroll
      for (int q = 0; q < 4; ++q) {
        xf[4*q+0] = cur[q].x; xf[4*q+1] = cur[q].y;
        xf[4*q+2] = cur[q].z; xf[4*q+3] = cur[q].w;
      }
    }
    #pragma unroll
    for (int q = 0; q < 4; ++q) {
      xf[16+4*q+0] = cur[4+q].x; xf[16+4*q+1] = cur[4+q].y;
      xf[16+4*q+2] = cur[4+q].z; xf[16+4*q+3] = cur[4+q].w;
    }

    // u exactly as all passing rounds (same summation order)
    float u[16];
    #pragma unroll
    for (int i = 0; i < 16; ++i) {
      float acc = w[0] * xf[1 + i];
      #pragma unroll
      for (int j = 1; j < KS; ++j) acc = fmaf(w[j], xf[1 + i + j], acc);
      u[i] = BETA_F * acc;
    }

    // lean LIF step: state update only (blind apply + rare exact repair)
    #pragma unroll
    for (int i = 0; i < 16; ++i) {
      float vr = fmaf(ALPHA_F, v, u[i]);
      float vm = vr - THETA_F;
      unsigned long long sp = __ballot(vr >= THETA_F);
      bool c1 = (vr >= THETA_F);
      v = c1 ? vm : vr;
      if (__builtin_expect((sp & (sp - 1ull)) != 0ull, 0)) {
        float m = wave64_max_all(vr);
        unsigned long long eq = __ballot(vr == m);
        bool win = (lane == __builtin_ctzll(eq));
        v = win ? vm : vr;
      }
    }

    cur[0] = cur[4]; cur[1] = cur[5]; cur[2] = cur[6]; cur[3] = cur[7];
    cur[4] = nx0;    cur[5] = nx1;    cur[6] = nx2;    cur[7] = nx3;
  }

  // ---------------- phase 2: output window --------------------------------
  for (int c = cout0; c < cend; ++c) {
    float4 nx0, nx1, nx2, nx3;
    {
      const int cn = (c + 1 < cend) ? (c + 1) : c;   // clamp on last chunk
      nx0 = xv4[4*cn + 0]; nx1 = xv4[4*cn + 1];
      nx2 = xv4[4*cn + 2]; nx3 = xv4[4*cn + 3];
    }

    float xf[32];
    if (c == 0) {
      #pragma unroll
      for (int m = 0; m < 16; ++m) xf[m] = 0.0f;
    } else {
      #pragma unroll
      for (int q = 0; q < 4; ++q) {
        xf[4*q+0] = cur[q].x; xf[4*q+1] = cur[q].y;
        xf[4*q+2] = cur[q].z; xf[4*q+3] = cur[q].w;
      }
    }
    #pragma unroll
    for (int q = 0; q < 4; ++q) {
      xf[16+4*q+0] = cur[4+q].x; xf[16+4*q+1] = cur[4+q].y;
      xf[16+4*q+2] = cur[4+q].z; xf[16+4*q+3] = cur[4+q].w;
    }

    float u[16];
    #pragma unroll
    for (int i = 0; i < 16; ++i) {
      float acc = w[0] * xf[1 + i];
      #pragma unroll
      for (int j = 1; j < KS; ++j) acc = fmaf(w[j], xf[1 + i + j], acc);
      u[i] = BETA_F * acc;
    }

    // full LIF+WTA step (verbatim R14/R15/R16 semantics)
    float sv[16];
    #pragma unroll
    for (int i = 0; i < 16; ++i) {
      float vr = fmaf(ALPHA_F, v, u[i]);
      float vm = vr - THETA_F;
      unsigned long long sp = __ballot(vr >= THETA_F);
      bool c1 = (vr >= THETA_F);
      sv[i] = c1 ? 1.0f : 0.0f;
      v     = c1 ? vm : vr;
      if (__builtin_expect((sp & (sp - 1ull)) != 0ull, 0)) {
        float m = wave64_max_all(vr);
        unsigned long long eq = __ballot(vr == m);
        bool win = (lane == __builtin_ctzll(eq));
        sv[i] = win ? 1.0f : 0.0f;
        v     = win ? vm : vr;
      }
    }

    float4* p = reinterpret_cast<float4*>(orow + (size_t)c * 16);
    p[0] = make_float4(sv[0],  sv[1],  sv[2],  sv[3]);
    p[1] = make_float4(sv[4],  sv[5],  sv[6],  sv[7]);
    p[2] = make_float4(sv[8],  sv[9],  sv[10], sv[11]);
    p[3] = make_float4(sv[12], sv[13], sv[14], sv[15]);

    cur[0] = cur[4]; cur[1] = cur[5]; cur[2] = cur[6]; cur[3] = cur[7];
    cur[4] = nx0;    cur[5] = nx1;    cur[6] = nx2;    cur[7] = nx3;
  }
}

extern "C" void kernel_launch(void* const* d_in, const int* in_sizes, int n_in,
                              void* d_out, int out_size, void* d_ws, size_t ws_size,
                              hipStream_t stream) {
  const float* x   = (const float*)d_in[0];
  const float* W   = (const float*)d_in[1];
  float*       out = (float*)d_out;
  convlif_wta_kernel<<<dim3(256 * NSEG), dim3(64), 0, stream>>>(x, W, out);
}

// Round 18
// 115.281 us; speedup vs baseline: 1.1161x; 1.1161x over previous
//
#include <hip/hip_runtime.h>

#define T_LEN  4096
#define KS     16
#define NSEG   8           // T segments (512 output steps each)
#define SEG_CH 32          // output chunks per segment
#define WARM_CH 24         // 384 warm-up steps (geometry identical to passing R17)

#define ALPHA_F 0.9048374180359595f
#define BETA_F  0.09516258196404048f
#define THETA_F 0.5f

// Full-wave (64-lane) max, result in ALL lanes. Verbatim from the passing
// R3-R17 kernels (manual s_nop hazard handling inside asm).
__device__ __forceinline__ float wave64_max_all(float v) {
  float m, t;
  asm("s_nop 1\n\t"
      "v_max_f32 %0, %2, %2 quad_perm:[1,0,3,2] row_mask:0xf bank_mask:0xf\n\t"
      "s_nop 1\n\t"
      "v_max_f32 %0, %0, %0 quad_perm:[2,3,0,1] row_mask:0xf bank_mask:0xf\n\t"
      "s_nop 1\n\t"
      "v_max_f32 %0, %0, %0 row_half_mirror row_mask:0xf bank_mask:0xf\n\t"
      "s_nop 1\n\t"
      "v_max_f32 %0, %0, %0 row_mirror row_mask:0xf bank_mask:0xf\n\t"
      "v_mov_b32 %1, %0\n\t"
      "s_nop 1\n\t"
      "v_permlane32_swap_b32 %1, %0\n\t"
      "s_nop 1\n\t"
      "v_max_f32 %0, %0, %1\n\t"
      "v_mov_b32 %1, %0\n\t"
      "s_nop 1\n\t"
      "v_permlane16_swap_b32 %1, %0\n\t"
      "s_nop 1\n\t"
      "v_max_f32 %0, %0, %1"
      : "=&v"(m), "=&v"(t)
      : "v"(v));
  return m;
}

__global__ __launch_bounds__(128, 4)
void convlif_wta_kernel(const float* __restrict__ x, const float* __restrict__ W,
                        float* __restrict__ out) {
  const int blk  = blockIdx.x;
  const int b    = blk >> 3;          // batch
  const int seg  = blk & (NSEG - 1);  // time segment
  const int wave = threadIdx.x >> 6;  // 0/1: ping-pong roles per chunk
  const int lane = threadIdx.x & 63;  // channel k

  const int cout0  = seg * SEG_CH;                                  // first output chunk
  const int cstart = (cout0 > WARM_CH) ? (cout0 - WARM_CH) : 0;     // warm-up start
  const int cend   = cout0 + SEG_CH;
  const int nch    = cend - cstart;   // 56 (seg>0) or 32 (seg 0)

  __shared__ float vbuf[2][64];       // v handoff ring (2 slots)

  // per-lane conv weights W[k][0..15] (verbatim)
  float w[KS];
  {
    const float4* w4 = reinterpret_cast<const float4*>(W + lane * KS);
    #pragma unroll
    for (int q = 0; q < 4; ++q) {
      float4 a = w4[q];
      w[4*q+0] = a.x; w[4*q+1] = a.y; w[4*q+2] = a.z; w[4*q+3] = a.w;
    }
  }

  const float4* xv4 = reinterpret_cast<const float4*>(x + (size_t)b * T_LEN);
  float* orow = out + ((size_t)(b * 64 + lane)) * T_LEN;   // this lane's channel row

  float u[16];   // conv results for my NEXT active chunk (lives across barrier)

  // conv for chunk c: u[i] = BETA * (w0*x[16c+i-15] + sum fma) — verbatim
  // summation order of all passing rounds. Fresh 8-quad window load (this
  // wave's consecutive chunks are 32 steps apart; windows don't overlap).
  auto conv_chunk = [&](int c) {
    float xf[32];
    if (c == 0) {
      #pragma unroll
      for (int m = 0; m < 16; ++m) xf[m] = 0.0f;
    } else {
      const int b4 = 4 * c - 4;
      #pragma unroll
      for (int q = 0; q < 4; ++q) {
        float4 a = xv4[b4 + q];
        xf[4*q+0] = a.x; xf[4*q+1] = a.y; xf[4*q+2] = a.z; xf[4*q+3] = a.w;
      }
    }
    #pragma unroll
    for (int q = 0; q < 4; ++q) {
      float4 a = xv4[4*c + q];
      xf[16+4*q+0] = a.x; xf[16+4*q+1] = a.y;
      xf[16+4*q+2] = a.z; xf[16+4*q+3] = a.w;
    }
    #pragma unroll
    for (int i = 0; i < 16; ++i) {
      float acc = w[0] * xf[1 + i];
      #pragma unroll
      for (int j = 1; j < KS; ++j) acc = fmaf(w[j], xf[1 + i + j], acc);
      u[i] = BETA_F * acc;
    }
  };

  // prologue: wave 0 computes conv for the first chunk (its s=0 active turn)
  if (wave == 0) conv_chunk(cstart);

  for (int s = 0; s < nch; ++s) {
    const int c = cstart + s;
    if ((s & 1) == wave) {
      // ---------- active: LIF + WTA on this chunk (verbatim R16 body) -----
      float v = (s == 0) ? 0.0f : vbuf[(s - 1) & 1][lane];
      float sv[16];
      #pragma unroll
      for (int i = 0; i < 16; ++i) {
        float vr = fmaf(ALPHA_F, v, u[i]);
        float vm = vr - THETA_F;
        unsigned long long sp = __ballot(vr >= THETA_F);
        bool c1 = (vr >= THETA_F);
        sv[i] = c1 ? 1.0f : 0.0f;
        v     = c1 ? vm : vr;
        if (__builtin_expect((sp & (sp - 1ull)) != 0ull, 0)) {
          float m = wave64_max_all(vr);
          unsigned long long eq = __ballot(vr == m);
          bool win = (lane == __builtin_ctzll(eq));
          sv[i] = win ? 1.0f : 0.0f;
          v     = win ? vm : vr;
        }
      }
      vbuf[s & 1][lane] = v;            // hand v to the other wave

      if (c >= cout0) {                 // store only in the output window
        float4* p = reinterpret_cast<float4*>(orow + (size_t)c * 16);
        p[0] = make_float4(sv[0],  sv[1],  sv[2],  sv[3]);
        p[1] = make_float4(sv[4],  sv[5],  sv[6],  sv[7]);
        p[2] = make_float4(sv[8],  sv[9],  sv[10], sv[11]);
        p[3] = make_float4(sv[12], sv[13], sv[14], sv[15]);
      }
    } else {
      // ---------- passive: conv my next chunk (c+1) -----------------------
      if (c + 1 < cend) conv_chunk(c + 1);
    }
    __syncthreads();   // orders vbuf write -> next iteration's read
  }
}

extern "C" void kernel_launch(void* const* d_in, const int* in_sizes, int n_in,
                              void* d_out, int out_size, void* d_ws, size_t ws_size,
                              hipStream_t stream) {
  const float* x   = (const float*)d_in[0];
  const float* W   = (const float*)d_in[1];
  float*       out = (float*)d_out;
  convlif_wta_kernel<<<dim3(256 * NSEG), dim3(128), 0, stream>>>(x, W, out);
}